// Round 14
// baseline (216.813 us; speedup 1.0000x reference)
//
#include <hip/hip_runtime.h>
#include <hip/hip_bf16.h>

typedef float  f32x4  __attribute__((ext_vector_type(4)));
typedef __bf16 bf16x8 __attribute__((ext_vector_type(8)));

#define SCALE_QK 0.17677669529663687f  /* 32^-0.5 (reference uses DIM_HEAD) */

// B=131072, L=4, dim=256, inner=32, heads=4, dh=8
// rows = 524288 ; 16-row tiles = 32768
// grid 1024 x 3 waves; slot = bid*3+wv; tiles strided by 3072 (10-11/wave)
// JOURNAL:
//  - VGPR cap law: cap = 256/(2nd launch_bounds arg); exceed -> spill.
//  - vmcnt in-order: per-tile vmem must be x-stage + out-stores ONLY.
//  - r11: NT loads/stores regressed (lost L3 residency).
//  - r12: contiguous-transaction theory NULL (230 ~= r9 232).
//  - r13: dbuf stage + counted vmcnt(16): 214us. BUT vmcnt(16) over-drains:
//    queue [loads(T),stores(T-1),loads(T+1)] -> 16 forces stores(T-1) retire
//    every iter (in-order counter).
//  - r14: steady-state vmcnt(32) = drain loads(T) ONLY; stores get a full
//    iteration of background slack. Prologue stages 2 tiles + vmcnt(16);
//    tail uses vmcnt(16) when no stage issued.

template<int CTRL>
__device__ __forceinline__ float dpp_add(float x) {
  int xi = __builtin_bit_cast(int, x);
  int yi = __builtin_amdgcn_mov_dpp(xi, CTRL, 0xF, 0xF, true);
  return x + __builtin_bit_cast(float, yi);
}

// ---------- prekernel: pack frag-ordered bf16 weights into d_ws ----------
// item = f*64 + lane, f in [0,64): wsf[item*8 + j]
// f in [0,48): GEMM1 frag (kt=f/6, ct=f%6): col n=ct*16+c, k=kt*32+g*8+j
// f in [48,64): Wo frag ct=f-48: col n=ct*16+c, k=g*8+j
__global__ void pack_weights(const float* __restrict__ Wq, const float* __restrict__ Wkv,
                             const float* __restrict__ Wo, __bf16* __restrict__ wsf) {
  const int item = blockIdx.x * 256 + threadIdx.x;   // 4096 items
  const int f = item >> 6, lane = item & 63;
  const int g = lane >> 4, c = lane & 15;
  union { bf16x8 v; __bf16 h[8]; } vv;
  if (f < 48) {
    const int kt = f / 6, ct = f - kt * 6;
    const int n = ct * 16 + c;
    #pragma unroll
    for (int j = 0; j < 8; ++j) {
      const int k = kt * 32 + g * 8 + j;
      vv.h[j] = (__bf16)((n < 32) ? Wq[k * 32 + n] : Wkv[k * 64 + (n - 32)]);
    }
  } else {
    const int ct = f - 48;
    const int n = ct * 16 + c;
    #pragma unroll
    for (int j = 0; j < 8; ++j) vv.h[j] = (__bf16)Wo[(g * 8 + j) * 256 + n];
  }
  *(bf16x8*)&wsf[item * 8] = vv.v;
}

#define FR1(f) (*(const bf16x8*)&wfrag1[(f) * 512 + lane * 8])
#define MFMA(a, b, cc) __builtin_amdgcn_mfma_f32_16x16x32_bf16((a), (b), (cc), 0, 0, 0)

// LDS map (bytes):
//   [0, 49152)        wfrag1 (GEMM1 frags 0..47): f*1024 + lane*16
//   [49152, 148992)   stage: wave wv, buf b at 49152 + wv*33280 + b*16640;
//                     row r at +r*1040 (1KB row + 16B pad)
//   [148992, 152832)  ao bounce: wave wv at +wv*1280 ([16][40] bf16)
//   [152832, 153856)  bo (256 f32)
//   [153856, 154112)  pe (64 f32)
#define LDS_TOTAL 154112

__global__ __launch_bounds__(192, 1) void fused_stattn(
    const float* __restrict__ x, const __bf16* __restrict__ wsf,
    const float* __restrict__ bo, const float* __restrict__ pe,
    float* __restrict__ out) {
  extern __shared__ char smem[];

  const int tid  = threadIdx.x;
  const int lane = tid & 63;
  const int wv   = tid >> 6;    // 0..2
  const int g    = lane >> 4;   // 16-lane group
  const int c    = lane & 15;   // col within fragment / A-row

  __bf16* wfrag1 = (__bf16*)smem;
  char*   stg0   = smem + 49152 + wv * 33280;          // wave-private dbuf base
  __bf16* aoW    = (__bf16*)(smem + 148992 + wv * 1280);
  float*  bo_l   = (float*)(smem + 152832);
  float*  pe_l   = (float*)(smem + 153856);

  // ---- Wo frags -> 64 regs (oldest in vmcnt queue; prologue vmcnt drains) ----
  bf16x8 wo[16];
  #pragma unroll
  for (int i = 0; i < 16; ++i)
    wo[i] = *(const bf16x8*)&wsf[((48 + i) * 64 + lane) * 8];

  // ---- GEMM1 frags + bo + pe -> LDS ----
  #pragma unroll
  for (int it = 0; it < 16; ++it) {
    const int idx = it * 192 + tid;                    // 3072 x 16B chunks
    *(bf16x8*)&wfrag1[idx * 8] = *(const bf16x8*)&wsf[idx * 8];
  }
  bo_l[tid] = bo[tid];
  if (tid < 64) bo_l[192 + tid] = bo[192 + tid];
  if (tid < 64) pe_l[tid] = pe[tid];
  __syncthreads();

  const unsigned stg_lds = (unsigned)(unsigned long long)(void*)stg0;

  // stage one 16x256 f32 tile: 16 instrs, each 64 lanes x 16B = contiguous 1KB
  auto stage_tile = [&](unsigned dbase, int tile) {
    const float* src = x + (size_t)tile * 4096 + (lane << 2);
    #pragma unroll
    for (int r = 0; r < 16; ++r) {
      __builtin_amdgcn_global_load_lds(
          (const __attribute__((address_space(1))) void*)(src + r * 256),
          (__attribute__((address_space(3))) void*)(unsigned long long)(dbase + r * 1040),
          16, 0, 0);
    }
  };

  const int slot = blockIdx.x * 3 + wv;    // 0..3071; every slot has >=10 tiles

  // ---- prologue: stage first two tiles; drain first (leave second flying) ----
  stage_tile(stg_lds, slot);
  stage_tile(stg_lds + 16640u, slot + 3072);
  asm volatile("s_waitcnt vmcnt(16)" ::: "memory");
  __builtin_amdgcn_sched_barrier(0);

  int cur = 0;
  for (int tile = slot; tile < 32768; tile += 3072) {
    char* stg = stg0 + cur * 16640;

    // ---- GEMM1: x[16x256] @ Wqkv[256x96]; A-frags from LDS stage ----
    f32x4 acc0 = {0,0,0,0}, acc1 = {0,0,0,0}, acc2 = {0,0,0,0};
    f32x4 acc3 = {0,0,0,0}, acc4 = {0,0,0,0}, acc5 = {0,0,0,0};
    #pragma unroll
    for (int kt = 0; kt < 8; ++kt) {
      const f32x4 va = *(const f32x4*)(stg + c * 1040 + kt * 128 + g * 32);
      const f32x4 vb = *(const f32x4*)(stg + c * 1040 + kt * 128 + g * 32 + 16);
      union { bf16x8 v; __bf16 h[8]; } af;    // A-frag: row=c, k = kt*32 + g*8 + j
      #pragma unroll
      for (int j = 0; j < 4; ++j) { af.h[j] = (__bf16)va[j]; af.h[4+j] = (__bf16)vb[j]; }
      acc0 = MFMA(af.v, FR1(kt*6+0), acc0);
      acc1 = MFMA(af.v, FR1(kt*6+1), acc1);
      acc2 = MFMA(af.v, FR1(kt*6+2), acc2);
      acc3 = MFMA(af.v, FR1(kt*6+3), acc3);
      acc4 = MFMA(af.v, FR1(kt*6+4), acc4);
      acc5 = MFMA(af.v, FR1(kt*6+5), acc5);
    }
    // C layout: lane(g,c) reg i -> row g*4+i (batch g, seq i), col c. q/k/v pairs.

    // ---- attention (in registers; 8-lane head-dim reduce via DPP) ----
    const int h0 = c >> 3;
    float ao0[4], ao1[4];
    #pragma unroll
    for (int p = 0; p < 2; ++p) {
      const f32x4 qa = p ? acc1 : acc0;
      const f32x4 ka = p ? acc3 : acc2;
      const f32x4 va = p ? acc5 : acc4;
      const int ph = 2 * p + h0;              // head owning cols p*16 + c
      float sim[4][4];
      #pragma unroll
      for (int i = 0; i < 4; ++i)
        #pragma unroll
        for (int j = 0; j < 4; ++j) {
          float pr = qa[i] * ka[j];
          pr = dpp_add<0xB1>(pr);             // quad_perm xor1
          pr = dpp_add<0x4E>(pr);             // quad_perm xor2
          pr = dpp_add<0x141>(pr);            // row_half_mirror
          sim[i][j] = pr * SCALE_QK + pe_l[ph * 16 + i * 4 + j];
        }
      #pragma unroll
      for (int i = 0; i < 4; ++i) {
        const float m = fmaxf(fmaxf(sim[i][0], sim[i][1]), fmaxf(sim[i][2], sim[i][3]));
        const float e0 = __expf(sim[i][0] - m), e1 = __expf(sim[i][1] - m);
        const float e2 = __expf(sim[i][2] - m), e3 = __expf(sim[i][3] - m);
        const float rs = 1.0f / (e0 + e1 + e2 + e3);
        const float o  = (e0*va[0] + e1*va[1] + e2*va[2] + e3*va[3]) * rs;
        if (p) ao1[i] = o; else ao0[i] = o;
      }
    }

    // ---- bounce C-layout -> B-frag layout for GEMM2 (per-wave private) ----
    #pragma unroll
    for (int i = 0; i < 4; ++i) {
      aoW[(g*4 + i) * 40 + c]      = (__bf16)ao0[i];
      aoW[(g*4 + i) * 40 + 16 + c] = (__bf16)ao1[i];
    }
    const bf16x8 a2 = *(const bf16x8*)&aoW[c * 40 + g * 8];  // col=c(=x-row), k=g*8+j

    // ---- GEMM2 (swapped): Wo^T @ ao^T, bias as C-input; D -> consumed stage buf ----
    #pragma unroll
    for (int ct = 0; ct < 16; ++ct) {
      const f32x4 bv = *(const f32x4*)&bo_l[ct * 16 + g * 4];
      f32x4 o = MFMA(wo[ct], a2, bv);
      // D: lane(g,c) reg i -> out row c, col ct*16 + g*4 + i
      *(f32x4*)(stg + c * 1040 + ct * 64 + g * 16) = o;
    }

    // ---- contiguous stores: row r = 64 lanes x 16B = 1KB per instr ----
    {
      float* orow = out + (size_t)tile * 4096 + (lane << 2);
      #pragma unroll
      for (int r = 0; r < 16; ++r) {
        const f32x4 v = *(const f32x4*)(stg + r * 1040 + lane * 16);
        *(f32x4*)(orow + r * 256) = v;
      }
    }

    // ---- buf(cur)'s LDS fully consumed (stores' ds_reads) -> refill it ----
    asm volatile("s_waitcnt lgkmcnt(0)" ::: "memory");
    const int t2 = tile + 2 * 3072;
    if (t2 < 32768) {
      stage_tile(stg_lds + (unsigned)(cur * 16640), t2);
      // queue: [stores(prev)? , loads(T+1), stores(T), loads(T+2)]
      // drain loads(T+1) only -> leave 32 newest in flight
      asm volatile("s_waitcnt vmcnt(32)" ::: "memory");
      __builtin_amdgcn_sched_barrier(0);
    } else if (tile + 3072 < 32768) {
      // no stage issued: queue = [stores(prev)?, loads(T+1), stores(T)]
      asm volatile("s_waitcnt vmcnt(16)" ::: "memory");
      __builtin_amdgcn_sched_barrier(0);
    }
    cur ^= 1;
  }
}

extern "C" void kernel_launch(void* const* d_in, const int* in_sizes, int n_in,
                              void* d_out, int out_size, void* d_ws, size_t ws_size,
                              hipStream_t stream) {
  const float* x   = (const float*)d_in[0];
  const float* Wq  = (const float*)d_in[1];
  const float* Wkv = (const float*)d_in[2];
  const float* Wo  = (const float*)d_in[3];
  const float* bo  = (const float*)d_in[4];
  const float* pe  = (const float*)d_in[5];
  float* out = (float*)d_out;
  __bf16* wsf = (__bf16*)d_ws;   // 64 KiB of frag-ordered bf16 weights

  (void)hipFuncSetAttribute(reinterpret_cast<const void*>(fused_stattn),
                            hipFuncAttributeMaxDynamicSharedMemorySize, LDS_TOTAL);
  hipLaunchKernelGGL(pack_weights, dim3(16), dim3(256), 0, stream, Wq, Wkv, Wo, wsf);
  hipLaunchKernelGGL(fused_stattn, dim3(1024), dim3(192), LDS_TOTAL, stream,
                     x, wsf, bo, pe, out);
}